// Round 1
// baseline (345.715 us; speedup 1.0000x reference)
//
#include <hip/hip_runtime.h>
#include <math.h>

#define HW 4096
#define NN 32
#define CC 64
#define CG 16

// ---------------------------------------------------------------------------
// Kernel A: grouped 3x3 offset conv.
// grid 2048 = 32 n * 4 g * 16 rowchunks ; block 256 = 4 rows x 64 cols.
// Each thread computes all 18 offset channels for one (n,g,h,w).
// ---------------------------------------------------------------------------
__global__ __launch_bounds__(256) void off_conv(const float* __restrict__ x,
                                                const float* __restrict__ w_off,
                                                const float* __restrict__ b_off,
                                                float* __restrict__ off)
{
    __shared__ float wl[144 * 18];   // [c*9+ij][d] for broadcast over d
    __shared__ float bl[18];
    int bx = blockIdx.x;
    int n  = bx >> 6;
    int rem = bx & 63;
    int g  = rem >> 4;
    int rc = rem & 15;
    int t  = threadIdx.x;

    for (int idx = t; idx < 2592; idx += 256) {
        int cij = idx / 18;
        int d   = idx - cij * 18;
        wl[cij * 18 + d] = w_off[(g * 18 + d) * 144 + cij];
    }
    if (t < 18) bl[t] = b_off[g * 18 + t];
    __syncthreads();

    int h = rc * 4 + (t >> 6);
    int w = t & 63;
    const float* xb = x + n * (CC * HW) + g * CG * HW;

    float acc[18];
    #pragma unroll
    for (int d = 0; d < 18; d++) acc[d] = bl[d];

    for (int c = 0; c < 16; c++) {
        const float* xc = xb + c * HW;
        #pragma unroll
        for (int i = 0; i < 3; i++) {
            int hh = h - 1 + i;
            bool vy = (hh >= 0) && (hh < 64);
            #pragma unroll
            for (int j = 0; j < 3; j++) {
                int ww = w - 1 + j;
                bool vx = (ww >= 0) && (ww < 64);
                float xv = (vy && vx) ? xc[hh * 64 + ww] : 0.f;
                const float* wp = &wl[(c * 9 + i * 3 + j) * 18];
                #pragma unroll
                for (int d = 0; d < 18; d++) acc[d] = fmaf(wp[d], xv, acc[d]);
            }
        }
    }

    int pos = h * 64 + w;
    float* ob = off + (n * 72 + g * 18) * HW + pos;
    #pragma unroll
    for (int d = 0; d < 18; d++) ob[d * HW] = acc[d];
}

// ---------------------------------------------------------------------------
// Kernel B: deformable bilinear gather + 16x16x9 contraction.
// grid 2048 = 32 n * 4 g * 16 chunks ; block 256 (one spatial pos / thread).
// ---------------------------------------------------------------------------
__global__ __launch_bounds__(256) void deform_conv(const float* __restrict__ x,
                                                   const float* __restrict__ off,
                                                   const float* __restrict__ w_dc,
                                                   const float* __restrict__ b_dc,
                                                   float* __restrict__ outpre)
{
    __shared__ float wl[2304];       // [c*9+k][o] for broadcast over o
    int bx = blockIdx.x;
    int n   = bx >> 6;
    int rem = bx & 63;
    int g   = rem >> 4;
    int chunk = rem & 15;
    int t = threadIdx.x;

    for (int idx = t; idx < 2304; idx += 256) {
        int ck = idx >> 4;
        int o  = idx & 15;
        wl[idx] = w_dc[(g * 16 + o) * 144 + ck];
    }
    __syncthreads();

    int pos = chunk * 256 + t;
    int h = pos >> 6;
    int w = pos & 63;
    const float* xb = x + n * (CC * HW) + g * CG * HW;
    const float* ob = off + (n * 72 + g * 18) * HW + pos;

    float acc[16];
    #pragma unroll
    for (int o = 0; o < 16; o++) acc[o] = b_dc[g * 16 + o];

    for (int k = 0; k < 9; k++) {
        float dy = ob[(k * 2 + 0) * HW];
        float dx = ob[(k * 2 + 1) * HW];
        float py = (float)(h - 1 + k / 3) + dy;
        float px = (float)(w - 1 + k % 3) + dx;
        float y0f = floorf(py), x0f = floorf(px);
        float ly = py - y0f, lx = px - x0f;
        int y0 = (int)y0f, x0 = (int)x0f;
        int y1 = y0 + 1,  x1 = x0 + 1;
        float vy0 = (y0 >= 0 && y0 < 64) ? 1.f : 0.f;
        float vy1 = (y1 >= 0 && y1 < 64) ? 1.f : 0.f;
        float vx0 = (x0 >= 0 && x0 < 64) ? 1.f : 0.f;
        float vx1 = (x1 >= 0 && x1 < 64) ? 1.f : 0.f;
        float w00 = (1.f - ly) * (1.f - lx) * vy0 * vx0;
        float w01 = (1.f - ly) * lx         * vy0 * vx1;
        float w10 = ly         * (1.f - lx) * vy1 * vx0;
        float w11 = ly         * lx         * vy1 * vx1;
        int yc0 = min(max(y0, 0), 63) * 64, yc1 = min(max(y1, 0), 63) * 64;
        int xc0 = min(max(x0, 0), 63),      xc1 = min(max(x1, 0), 63);
        int i00 = yc0 + xc0, i01 = yc0 + xc1, i10 = yc1 + xc0, i11 = yc1 + xc1;

        #pragma unroll
        for (int c = 0; c < 16; c++) {
            const float* xc = xb + c * HW;
            float val = w00 * xc[i00] + w01 * xc[i01]
                      + w10 * xc[i10] + w11 * xc[i11];
            const float* wp = &wl[(c * 9 + k) * 16];
            #pragma unroll
            for (int o = 0; o < 16; o++) acc[o] = fmaf(wp[o], val, acc[o]);
        }
    }

    float* op = outpre + (n * 64 + g * 16) * HW + pos;
    #pragma unroll
    for (int o = 0; o < 16; o++) op[o * HW] = acc[o];
}

// ---------------------------------------------------------------------------
// Kernel C: per-(n,cout) spatial mean/var + exact GELU + transposed store.
// grid 2048 = 32 n * 64 cout ; block 256 ; 16 values/thread in registers.
// ---------------------------------------------------------------------------
__global__ __launch_bounds__(256) void norm_gelu(const float* __restrict__ outpre,
                                                 float* __restrict__ out)
{
    __shared__ float red[8];
    int bx = blockIdx.x;
    int n  = bx >> 6;
    int co = bx & 63;
    int t  = threadIdx.x;

    const float4* base = (const float4*)(outpre + (n * 64 + co) * HW);
    float4 v[4];
    float s = 0.f;
    #pragma unroll
    for (int r = 0; r < 4; r++) {
        v[r] = base[t + r * 256];
        s += v[r].x + v[r].y + v[r].z + v[r].w;
    }
    #pragma unroll
    for (int o2 = 32; o2 > 0; o2 >>= 1) s += __shfl_down(s, o2, 64);
    int wid = t >> 6, lane = t & 63;
    if (lane == 0) red[wid] = s;
    __syncthreads();
    float mean = (red[0] + red[1] + red[2] + red[3]) * (1.f / 4096.f);

    float sq = 0.f;
    #pragma unroll
    for (int r = 0; r < 4; r++) {
        float a = v[r].x - mean, b = v[r].y - mean;
        float c = v[r].z - mean, d = v[r].w - mean;
        sq += a * a + b * b + c * c + d * d;
    }
    #pragma unroll
    for (int o2 = 32; o2 > 0; o2 >>= 1) sq += __shfl_down(sq, o2, 64);
    if (lane == 0) red[4 + wid] = sq;
    __syncthreads();
    float var  = (red[4] + red[5] + red[6] + red[7]) * (1.f / 4096.f);
    float rstd = rsqrtf(var + 1e-5f);

    int b = n >> 3, d = n & 7;
    float4* outp = (float4*)(out + (((b * 64 + co) * 8) + d) * HW);
    #pragma unroll
    for (int r = 0; r < 4; r++) {
        float xs[4] = {v[r].x, v[r].y, v[r].z, v[r].w};
        float4 res;
        float* rp = (float*)&res;
        #pragma unroll
        for (int q = 0; q < 4; q++) {
            float xn = (xs[q] - mean) * rstd;
            rp[q] = 0.5f * xn * (1.f + erff(xn * 0.70710678118654752f));
        }
        outp[t + r * 256] = res;
    }
}

// ---------------------------------------------------------------------------
extern "C" void kernel_launch(void* const* d_in, const int* in_sizes, int n_in,
                              void* d_out, int out_size, void* d_ws, size_t ws_size,
                              hipStream_t stream) {
    const float* x     = (const float*)d_in[0];
    const float* w_off = (const float*)d_in[1];
    const float* b_off = (const float*)d_in[2];
    const float* w_dc  = (const float*)d_in[3];
    const float* b_dc  = (const float*)d_in[4];
    float* out = (float*)d_out;

    float* offbuf = (float*)d_ws;                      // 32*72*4096 floats = 37.75 MB
    float* outpre = offbuf + NN * 72 * HW;             // 32*64*4096 floats = 33.55 MB

    off_conv  <<<2048, 256, 0, stream>>>(x, w_off, b_off, offbuf);
    deform_conv<<<2048, 256, 0, stream>>>(x, offbuf, w_dc, b_dc, outpre);
    norm_gelu <<<2048, 256, 0, stream>>>(outpre, out);
}